// Round 5
// baseline (244.755 us; speedup 1.0000x reference)
//
#include <hip/hip_runtime.h>
#include <hip/hip_bf16.h>

#define N_SITES 200000
#define CIN 256
#define CMID 64
#define KVOL 9

using bf16x8 = __attribute__((ext_vector_type(8))) short;
using f32x4  = __attribute__((ext_vector_type(4))) float;

__device__ __forceinline__ short f2bf(float f) {
    union { float f; unsigned u; } v; v.f = f;
    unsigned r = v.u + 0x7fffu + ((v.u >> 16) & 1u);   // RNE
    return (short)(r >> 16);
}

__device__ __forceinline__ f32x4 mfma16(bf16x8 a, bf16x8 b, f32x4 c) {
    return __builtin_amdgcn_mfma_f32_16x16x32_bf16(a, b, c, 0, 0, 0);
}

// ---------------- K0: pre-convert W2,W3 to bf16 transposed (co-major) layouts
// W2T[kk][co][k] = bf(W2[kk][k][co]);  W3T[co][k] = bf(W3[k][co])
__global__ __launch_bounds__(256) void k0_convert(const float* __restrict__ W2,
                                                  const float* __restrict__ W3,
                                                  short* __restrict__ W2T,
                                                  short* __restrict__ W3T) {
    int t = blockIdx.x * 256 + threadIdx.x;
    if (t < KVOL * CMID * CMID) {
        int kk = t >> 12, rem = t & 4095, co = rem >> 6, k = rem & 63;
        W2T[t] = f2bf(W2[kk * 4096 + k * 64 + co]);
    }
    if (t < CMID * CIN) {
        int co = t >> 6, k = t & 63;
        W3T[t] = f2bf(W3[k * 256 + co]);
    }
}

// ---------------- K1: x1 = relu(feat @ W1)  (unchanged — at BW ceiling)
__global__ __launch_bounds__(256) void k1_conv1(const float* __restrict__ feat,
                                                const float* __restrict__ W1,
                                                short* __restrict__ x1) {
    __shared__ short w1t[64][264];   // W1^T
    __shared__ short o1[64][72];     // bf16 out staging
    const int t = threadIdx.x;
    const int lane = t & 63, w = t >> 6;
    const int r = lane & 15, g = lane >> 4;

    #pragma unroll
    for (int q = 0; q < 16; ++q) {
        int k0 = 4 * w + 16 * q;
        float v0 = W1[(k0 + 0) * 64 + lane];
        float v1 = W1[(k0 + 1) * 64 + lane];
        float v2 = W1[(k0 + 2) * 64 + lane];
        float v3 = W1[(k0 + 3) * 64 + lane];
        *(short4*)&w1t[lane][k0] = make_short4(f2bf(v0), f2bf(v1), f2bf(v2), f2bf(v3));
    }
    __syncthreads();

    const int row0 = blockIdx.x * 64 + w * 16;
    const float* ap = feat + (size_t)(row0 + r) * CIN + g * 8;

    f32x4 acc[4] = {};
    #pragma unroll
    for (int ks = 0; ks < 8; ++ks) {
        f32x4 a0 = *(const f32x4*)(ap + ks * 32);
        f32x4 a1 = *(const f32x4*)(ap + ks * 32 + 4);
        bf16x8 af;
        #pragma unroll
        for (int j = 0; j < 4; ++j) { af[j] = f2bf(a0[j]); af[4 + j] = f2bf(a1[j]); }
        #pragma unroll
        for (int ct = 0; ct < 4; ++ct) {
            bf16x8 bf = *(const bf16x8*)&w1t[ct * 16 + r][ks * 32 + g * 8];
            acc[ct] = mfma16(af, bf, acc[ct]);
        }
    }
    #pragma unroll
    for (int ct = 0; ct < 4; ++ct)
        #pragma unroll
        for (int j = 0; j < 4; ++j) {
            float v = acc[ct][j];
            o1[w * 16 + g * 4 + j][ct * 16 + r] = f2bf(v > 0.f ? v : 0.f);
        }
    __syncthreads();
    #pragma unroll
    for (int i = 0; i < 2; ++i) {
        int v = t + 256 * i; int row = v >> 3, c8 = v & 7;
        *(bf16x8*)&x1[(size_t)(blockIdx.x * 64 + row) * CMID + c8 * 8] =
            *(const bf16x8*)&o1[row][c8 * 8];
    }
}

// ---------------- K23: fused conv2+relu+conv3+residual+relu — ZERO barriers
__global__ __launch_bounds__(256, 4) void k23_fused(const short* __restrict__ x1,
                                                    const short* __restrict__ W2T,
                                                    const short* __restrict__ W3T,
                                                    const int* __restrict__ nbr,
                                                    const float* __restrict__ feat,
                                                    float* __restrict__ out) {
    __shared__ short o2[4][16][72];   // per-wave x2 tile (9.2 KB)
    __shared__ float ot[4][16][36];   // per-wave out staging chunk (9.2 KB)
    const int t = threadIdx.x;
    const int lane = t & 63, w = t >> 6;
    const int r = lane & 15, g = lane >> 4;

    // bijective XCD swizzle (3125 % 8 = 5)
    const int nwg = gridDim.x;
    const int q = nwg >> 3, rm = nwg & 7;
    const int xcd = blockIdx.x & 7, pos = blockIdx.x >> 3;
    const int bid = (xcd < rm) ? xcd * (q + 1) + pos
                               : rm * (q + 1) + (xcd - rm) * q + pos;

    const int row0 = bid * 64 + w * 16;
    const int site = row0 + r;

    int idx9[9];
    #pragma unroll
    for (int kk = 0; kk < 9; ++kk) idx9[kk] = nbr[site * 9 + kk];

    // ---- conv2: gather pipeline depth 2, B-frags straight from global (L1/L2-hot)
    bf16x8 a0p[2] = {}, a1p[2] = {};
    #pragma unroll
    for (int p = 0; p < 2; ++p) {
        int ii = idx9[p];
        if (ii >= 0) { const short* gp = x1 + (size_t)ii * CMID + g * 8;
                       a0p[p] = *(const bf16x8*)gp; a1p[p] = *(const bf16x8*)(gp + 32); }
    }

    f32x4 acc2[4] = {};
    #pragma unroll
    for (int kk = 0; kk < 9; ++kk) {
        const int cur = kk & 1;
        bf16x8 a0 = a0p[cur], a1 = a1p[cur];
        bf16x8 n0 = {}, n1 = {};
        if (kk + 2 < 9) {
            int ii = idx9[kk + 2];
            if (ii >= 0) { const short* gp = x1 + (size_t)ii * CMID + g * 8;
                           n0 = *(const bf16x8*)gp; n1 = *(const bf16x8*)(gp + 32); }
        }
        a0p[cur] = n0; a1p[cur] = n1;
        const short* bp = W2T + kk * 4096 + r * 64 + g * 8;
        #pragma unroll
        for (int ct = 0; ct < 4; ++ct) {
            bf16x8 b0 = *(const bf16x8*)(bp + ct * 1024);
            bf16x8 b1 = *(const bf16x8*)(bp + ct * 1024 + 32);
            acc2[ct] = mfma16(a0, b0, acc2[ct]);
            acc2[ct] = mfma16(a1, b1, acc2[ct]);
        }
    }

    // ---- wave-private x2 bounce (C-layout -> A-fragments), no barrier
    #pragma unroll
    for (int ct = 0; ct < 4; ++ct)
        #pragma unroll
        for (int j = 0; j < 4; ++j) {
            float v = acc2[ct][j];
            o2[w][g * 4 + j][ct * 16 + r] = f2bf(v > 0.f ? v : 0.f);
        }
    asm volatile("s_waitcnt lgkmcnt(0)" ::: "memory");
    bf16x8 a0 = *(const bf16x8*)&o2[w][r][g * 8];
    bf16x8 a1 = *(const bf16x8*)&o2[w][r][32 + g * 8];

    // ---- conv3: B-frags straight from global W3T (L1/L2-hot)
    f32x4 acc3[16];
    const short* wp = W3T + r * 64 + g * 8;
    #pragma unroll
    for (int ct = 0; ct < 16; ++ct) {
        bf16x8 b0 = *(const bf16x8*)(wp + ct * 1024);
        bf16x8 b1 = *(const bf16x8*)(wp + ct * 1024 + 32);
        f32x4 z = {};
        z = mfma16(a0, b0, z);
        acc3[ct] = mfma16(a1, b1, z);
    }

    // ---- epilogue: 8x32-col chunks, wave-private staging, feat prefetched 1 ahead
    const int row_l = lane >> 2, c8v = lane & 3;
    const size_t fbase = (size_t)(row0 + row_l) * CIN + c8v * 8;
    f32x4 f0 = __builtin_nontemporal_load((const f32x4*)&feat[fbase]);
    f32x4 f1 = __builtin_nontemporal_load((const f32x4*)&feat[fbase + 4]);
    #pragma unroll
    for (int c = 0; c < 8; ++c) {
        #pragma unroll
        for (int ci = 0; ci < 2; ++ci)
            #pragma unroll
            for (int j = 0; j < 4; ++j)
                ot[w][g * 4 + j][ci * 16 + r] = acc3[c * 2 + ci][j];
        f32x4 fn0 = f0, fn1 = f1;
        if (c < 7) {
            fn0 = __builtin_nontemporal_load((const f32x4*)&feat[fbase + (c + 1) * 32]);
            fn1 = __builtin_nontemporal_load((const f32x4*)&feat[fbase + (c + 1) * 32 + 4]);
        }
        asm volatile("s_waitcnt lgkmcnt(0)" ::: "memory");
        f32x4 s0 = *(const f32x4*)&ot[w][row_l][c8v * 8];
        f32x4 s1 = *(const f32x4*)&ot[w][row_l][c8v * 8 + 4];
        f32x4 r0v, r1v;
        #pragma unroll
        for (int j = 0; j < 4; ++j) {
            float x0 = s0[j] + f0[j]; r0v[j] = x0 > 0.f ? x0 : 0.f;
            float x1v = s1[j] + f1[j]; r1v[j] = x1v > 0.f ? x1v : 0.f;
        }
        __builtin_nontemporal_store(r0v, (f32x4*)&out[fbase + c * 32]);
        __builtin_nontemporal_store(r1v, (f32x4*)&out[fbase + c * 32 + 4]);
        f0 = fn0; f1 = fn1;
    }
}

extern "C" void kernel_launch(void* const* d_in, const int* in_sizes, int n_in,
                              void* d_out, int out_size, void* d_ws, size_t ws_size,
                              hipStream_t stream) {
    const float* feat = (const float*)d_in[0];
    const float* W1   = (const float*)d_in[1];
    const float* W2   = (const float*)d_in[2];
    const float* W3   = (const float*)d_in[3];
    const int*   nbr  = (const int*)d_in[4];

    short* x1  = (short*)d_ws;                          // [N,64] bf16, 25.6 MB
    short* W2T = x1 + (size_t)N_SITES * CMID;           // [9][64][64] bf16
    short* W3T = W2T + KVOL * CMID * CMID;              // [256][64] bf16
    float* out = (float*)d_out;

    const int blocks = N_SITES / 64;                    // 3125
    hipLaunchKernelGGL(k0_convert, dim3(144), dim3(256), 0, stream, W2, W3, W2T, W3T);
    hipLaunchKernelGGL(k1_conv1, dim3(blocks), dim3(256), 0, stream, feat, W1, x1);
    hipLaunchKernelGGL(k23_fused, dim3(blocks), dim3(256), 0, stream,
                       x1, W2T, W3T, nbr, feat, out);
}